// Round 4
// baseline (1145.534 us; speedup 1.0000x reference)
//
#include <hip/hip_runtime.h>
#include <hip/hip_bf16.h>

// Problem: B=32, C=2048, Q=128, E=200. Inputs fp32, OUTPUT fp32 (B,C,4E).
// (R2/R3 failed by writing bf16 into the fp32 d_out — identical 7.03 absmax
//  from two different kernels was the tell: segment-0 copy garbled the same way.)
#define B_ 32
#define C_ 2048
#define Q_ 128
#define E_ 200

// ---------------------------------------------------------------- K1
// s_q[b,q] = dot(x_q[b,q,:], w2)
__global__ __launch_bounds__(128) void sq_kernel(const float* __restrict__ xq,
                                                 const float* __restrict__ w,
                                                 float* __restrict__ sq) {
    const int b = blockIdx.x, q = threadIdx.x;
    const float* row = xq + ((size_t)b * Q_ + q) * E_;
    float a = 0.f;
    for (int e = 0; e < E_; ++e) a = fmaf(row[e], w[E_ + e], a);
    sq[b * Q_ + q] = a;
}

// ---------------------------------------------------------------- K2
// One block per (b,c): S[q] (q=thread), row max -> m_g, softmax, c2q,
// output segments 0..3E. All fp32; x_q read from global (L2-resident, 3.3 MB).
__global__ __launch_bounds__(128) void row_kernel(const float* __restrict__ xc_g,
                                                  const float* __restrict__ xq_g,
                                                  const float* __restrict__ w_g,
                                                  const float* __restrict__ sq_g,
                                                  float* __restrict__ m_g,
                                                  float* __restrict__ out) {
    __shared__ float xc_l[E_];
    __shared__ float scw3[E_];
    __shared__ float P_l[Q_];
    __shared__ float red[2];

    const int t  = threadIdx.x;          // 0..127 (2 waves)
    const int bc = blockIdx.x;           // b*C_ + c
    const int b  = bc / C_;
    const float* xc_row = xc_g + (size_t)bc * E_;
    const float* xq_b   = xq_g + (size_t)b * Q_ * E_;

    // ---- stage xc row, xc*w3; partial s_c = xc . w1 ----
    float p1 = 0.f;
    for (int e = t; e < E_; e += 128) {
        const float v = xc_row[e];
        xc_l[e] = v;
        scw3[e] = v * w_g[2 * E_ + e];
        p1 = fmaf(v, w_g[e], p1);
    }
    #pragma unroll
    for (int off = 32; off; off >>= 1) p1 += __shfl_xor(p1, off);
    if ((t & 63) == 0) red[t >> 6] = p1;
    __syncthreads();                                      // (A) scw3/xc_l/red visible
    const float s_c = red[0] + red[1];

    // ---- S for q = t ----
    const float* qrow = xq_b + t * E_;
    float s = 0.f;
    for (int e = 0; e < E_; ++e) s = fmaf(scw3[e], qrow[e], s);
    s += s_c + sq_g[b * Q_ + t];

    // ---- row max ----
    float mx = s;
    #pragma unroll
    for (int off = 32; off; off >>= 1) mx = fmaxf(mx, __shfl_xor(mx, off));
    __syncthreads();                                      // (B) all reads of red done
    if ((t & 63) == 0) red[t >> 6] = mx;
    __syncthreads();                                      // (C)
    const float mrow = fmaxf(red[0], red[1]);
    if (t == 0) m_g[bc] = mrow;

    // ---- exp & denom ----
    const float p = __expf(s - mrow);
    P_l[t] = p;
    float sm = p;
    #pragma unroll
    for (int off = 32; off; off >>= 1) sm += __shfl_xor(sm, off);
    __syncthreads();                                      // (D) mrow reads done
    if ((t & 63) == 0) red[t >> 6] = sm;
    __syncthreads();                                      // (E) red + P_l visible
    const float inv = 1.f / (red[0] + red[1]);

    // ---- c2q + output segments 0..3E ----
    float* orow = out + (size_t)bc * (4 * E_);
    for (int e = t; e < E_; e += 128) {
        float acc = 0.f;
        for (int q = 0; q < Q_; ++q) acc = fmaf(P_l[q], xq_b[q * E_ + e], acc);
        const float c2q = acc * inv;
        const float xcv = xc_l[e];
        orow[e]          = xcv;
        orow[E_ + e]     = c2q;
        orow[2 * E_ + e] = xcv * c2q;
    }
}

// ---------------------------------------------------------------- K3
// per-b max & denominator over m[b, 0:C]
__global__ __launch_bounds__(256) void stats_kernel(const float* __restrict__ m_g,
                                                    float* __restrict__ bstat) {
    __shared__ float red[4];
    const int b = blockIdx.x, t = threadIdx.x;
    float mx = -3.4e38f;
    for (int c = t; c < C_; c += 256) mx = fmaxf(mx, m_g[b * C_ + c]);
    #pragma unroll
    for (int off = 32; off; off >>= 1) mx = fmaxf(mx, __shfl_xor(mx, off));
    if ((t & 63) == 0) red[t >> 6] = mx;
    __syncthreads();
    mx = fmaxf(fmaxf(red[0], red[1]), fmaxf(red[2], red[3]));
    __syncthreads();
    float sum = 0.f;
    for (int c = t; c < C_; c += 256) sum += __expf(m_g[b * C_ + c] - mx);
    #pragma unroll
    for (int off = 32; off; off >>= 1) sum += __shfl_xor(sum, off);
    if ((t & 63) == 0) red[t >> 6] = sum;
    __syncthreads();
    if (t == 0) {
        bstat[b]      = mx;
        bstat[B_ + b] = red[0] + red[1] + red[2] + red[3];
    }
}

// ---------------------------------------------------------------- K4
// q2c[b,e] = sum_c softmax_c(m)[c] * xc[b,c,e]   (one block per b)
__global__ __launch_bounds__(256) void q2c_kernel(const float* __restrict__ xc_g,
                                                  const float* __restrict__ m_g,
                                                  const float* __restrict__ bstat,
                                                  float* __restrict__ q2c) {
    __shared__ float wl[C_];   // 8 KB
    const int b = blockIdx.x, t = threadIdx.x;
    const float mx  = bstat[b];
    const float inv = 1.f / bstat[B_ + b];
    for (int c = t; c < C_; c += 256) wl[c] = __expf(m_g[b * C_ + c] - mx) * inv;
    __syncthreads();
    if (t < E_) {
        float acc = 0.f;
        for (int c = 0; c < C_; ++c)
            acc = fmaf(wl[c], xc_g[((size_t)(b * C_ + c)) * E_ + t], acc);
        q2c[b * E_ + t] = acc;
    }
}

// ---------------------------------------------------------------- K5
// out[..., 3E:4E] = x_c * q2c (broadcast over c)
__global__ __launch_bounds__(256) void out4_kernel(const float* __restrict__ xc_g,
                                                   const float* __restrict__ q2c,
                                                   float* __restrict__ out) {
    const unsigned int idx = blockIdx.x * 256u + threadIdx.x;  // < B*C*E
    const unsigned int e = idx % E_;
    const unsigned int row = idx / E_;   // b*C + c
    const unsigned int b = row / C_;
    const float v = xc_g[idx] * q2c[b * E_ + e];
    out[(size_t)row * (4 * E_) + 3 * E_ + e] = v;
}

extern "C" void kernel_launch(void* const* d_in, const int* in_sizes, int n_in,
                              void* d_out, int out_size, void* d_ws, size_t ws_size,
                              hipStream_t stream) {
    // order-robust input selection by element count
    const float* xc = (const float*)d_in[0];
    const float* xq = (const float*)d_in[1];
    const float* w  = (const float*)d_in[2];
    for (int i = 0; i < n_in; ++i) {
        if      (in_sizes[i] == B_ * C_ * E_) xc = (const float*)d_in[i];
        else if (in_sizes[i] == B_ * Q_ * E_) xq = (const float*)d_in[i];
        else if (in_sizes[i] == 3 * E_)       w  = (const float*)d_in[i];
    }
    float* out = (float*)d_out;

    float* ws    = (float*)d_ws;
    float* sq    = ws;                 // B*Q   = 4096
    float* m     = sq + B_ * Q_;       // B*C   = 65536
    float* bstat = m + B_ * C_;        // 2*B   = 64
    float* q2c   = bstat + 2 * B_;     // B*E   = 6400   (total 304 KB)

    sq_kernel  <<<B_,          128, 0, stream>>>(xq, w, sq);
    row_kernel <<<B_ * C_,     128, 0, stream>>>(xc, xq, w, sq, m, out);
    stats_kernel<<<B_,         256, 0, stream>>>(m, bstat);
    q2c_kernel <<<B_,          256, 0, stream>>>(xc, m, bstat, q2c);
    out4_kernel<<<(B_ * C_ * E_) / 256, 256, 0, stream>>>(xc, q2c, out);
}